// Round 5
// baseline (4892.959 us; speedup 1.0000x reference)
//
#include <hip/hip_runtime.h>

typedef unsigned short U16;
typedef unsigned int   U32;
typedef unsigned long long U64;
typedef __attribute__((ext_vector_type(8))) short S8;
typedef __attribute__((ext_vector_type(4))) float F4;

#define B_  64
#define T_  512
#define DD  768
#define HH  384
#define G4  1536
#define NL  33

__device__ __forceinline__ U16 f2bf(float f){
  U32 u = __float_as_uint(f);
  u += 0x7fffu + ((u >> 16) & 1u);
  return (U16)(u >> 16);
}
__device__ __forceinline__ float bf2f(U16 h){ return __uint_as_float(((U32)h) << 16); }
__device__ __forceinline__ float frcp(float x){
  float r;
  asm("v_rcp_f32 %0, %1" : "=v"(r) : "v"(x));
  return r * (2.0f - x * r);   // 1 Newton step
}
__device__ __forceinline__ float sigm(float x){
  return frcp(1.f + __expf(-x));
}
__device__ __forceinline__ float tanh_(float x){
  float e = __expf(2.f * x);
  return 1.f - 2.f * frcp(e + 1.f);
}

// ---------------- fused: lengths + weight casts + x cast ----------------
__global__ void k_pre(const float* x, U64* xb, const U32* mask, int* lens,
                      const float* wf_, const float* wb_, const float* lw_,
                      const float* bfv, const float* bbv,
                      U16* wcat, U16* lwb, float* bcat){
  int blk = blockIdx.x;
  int tid = threadIdx.x;
  if (blk < 64){
    if (tid < 64){
      int b = blk, l = tid;
      bool b32 = (mask[0] == 1u);   // int32 mask: word0==1; bool mask: 0x01010101
      int cnt = 0;
      for (int t = l; t < T_; t += 64){
        int v = b32 ? ((const int*)mask)[b * T_ + t]
                    : (int)((const unsigned char*)mask)[b * T_ + t];
        cnt += (v != 0);
      }
      #pragma unroll
      for (int o = 32; o >= 1; o >>= 1) cnt += __shfl_xor(cnt, o);
      if (l == 0) lens[b] = cnt;
    }
    return;
  }
  if (blk < 1088){
    const int WE = G4 * DD;
    const int LWE = NL * DD;
    int total = 2 * WE + LWE + 2 * G4;
    for (int i = (blk - 64) * 256 + tid; i < total; i += 1024 * 256){
      if (i < WE) wcat[i] = f2bf(wf_[i]);
      else if (i < 2 * WE) wcat[i] = f2bf(wb_[i - WE]);
      else if (i < 2 * WE + LWE) lwb[i - 2 * WE] = f2bf(lw_[i - 2 * WE]);
      else { int j = i - 2 * WE - LWE; bcat[j] = (j < G4) ? bfv[j] : bbv[j - G4]; }
    }
    return;
  }
  size_t n4 = (size_t)B_ * T_ * DD / 4;
  for (size_t i = (size_t)(blk - 1088) * 256 + tid; i < n4; i += (size_t)2048 * 256){
    float4 v = ((const float4*)x)[i];
    U64 o = (U64)f2bf(v.x) | ((U64)f2bf(v.y) << 16) | ((U64)f2bf(v.z) << 32) | ((U64)f2bf(v.w) << 48);
    xb[i] = o;
  }
}

// ---------------- xp GEMM: [32768 x 768] x [3072 x 768]^T + bias -> bf16 ----------------
__global__ __launch_bounds__(256) void k_gemm(const U16* A, const U16* Bw, const float* bias, U16* C){
  __shared__ __align__(16) U16 As[128 * 64];
  __shared__ __align__(16) U16 Bs[128 * 64];
  int bid = blockIdx.x;
  int nb = bid % 24, mb = bid / 24;
  int m0 = mb * 128, n0 = nb * 128;
  int tid = threadIdx.x;
  int w = tid >> 6, l = tid & 63;
  int lr = l & 15, lk = (l >> 4) * 8;
  int wm = (w >> 1) * 64, wn = (w & 1) * 64;
  int srow = tid >> 3;
  int scol = (tid & 7) * 8;
  F4 acc[4][4];
  #pragma unroll
  for (int i = 0; i < 4; i++)
    #pragma unroll
    for (int j = 0; j < 4; j++) acc[i][j] = (F4){0.f, 0.f, 0.f, 0.f};

  for (int kt = 0; kt < DD; kt += 64){
    __syncthreads();
    #pragma unroll
    for (int r = 0; r < 4; r++){
      int row = r * 32 + srow;
      __builtin_amdgcn_global_load_lds((const U32*)(A + (size_t)(m0 + row) * DD + kt + scol),
                                       (U32*)(As + row * 64 + scol), 16, 0, 0);
      __builtin_amdgcn_global_load_lds((const U32*)(Bw + (size_t)(n0 + row) * DD + kt + scol),
                                       (U32*)(Bs + row * 64 + scol), 16, 0, 0);
    }
    __syncthreads();
    #pragma unroll
    for (int kk = 0; kk < 64; kk += 32){
      S8 af[4], bf[4];
      #pragma unroll
      for (int i = 0; i < 4; i++) af[i] = *(const S8*)(As + (wm + i * 16 + lr) * 64 + kk + lk);
      #pragma unroll
      for (int i = 0; i < 4; i++) bf[i] = *(const S8*)(Bs + (wn + i * 16 + lr) * 64 + kk + lk);
      #pragma unroll
      for (int i = 0; i < 4; i++)
        #pragma unroll
        for (int j = 0; j < 4; j++)
          acc[i][j] = __builtin_amdgcn_mfma_f32_16x16x32_bf16(af[i], bf[j], acc[i][j], 0, 0, 0);
    }
  }
  #pragma unroll
  for (int j = 0; j < 4; j++){
    int col = n0 + wn + j * 16 + lr;
    float bv = bias[col];
    #pragma unroll
    for (int i = 0; i < 4; i++){
      #pragma unroll
      for (int rg = 0; rg < 4; rg++){
        int row = m0 + wm + i * 16 + (l >> 4) * 4 + rg;
        C[(size_t)row * 3072 + col] = f2bf(acc[i][j][rg] + bv);
      }
    }
  }
}

// ---------------- LSTM recurrence: 4-chunk interleave, agent-scope tagged exchange ----
// 12 blocks = 6 members x 2 dirs. Block (m,dir) holds gate-rows {q*384 + m*64 + ...} of
// w_hh_dir in VGPRs (192/thread) and advances FOUR independent 16-seq chunks per round.
// Exchange protocol identical to round 3 (proven): hx word (U64) = [tag:32 | row(2p+1)
// bf16 | row(2p) bf16], word = g*3072 + j*8 + p, g = dir*4+chunk, parity = tag&1 region.
// Publish of round r carries tag r+1 into parity (r+1)&1; consumer at round r polls for
// tag==r. Poll covers all 3072 words (all members incl. own block's waves) -> a wave
// enters round r only after every producer finished round r-1: protects LDS hl WAR and
// parity-buffer reuse. Visibility latency (~1.3us via L3) is paid once per 4-chunk
// round, not per step: while chunk c's publish propagates, chunks c+1..3 compute.
__global__ __launch_bounds__(256, 1) void k_rec(const U16* __restrict__ xp,
                                                const float* __restrict__ whf,
                                                const float* __restrict__ whb,
                                                const int* __restrict__ len_,
                                                U16* __restrict__ hcat, U64* hx){
  int blk = blockIdx.x;
  int m = blk % 6, dir = blk / 6;
  const float* wh = dir ? whb : whf;
  int tid = threadIdx.x;
  int w = tid >> 6, l = tid & 63;
  int lr = l & 15, lq = l >> 4;
  int jloc = m * 64 + w * 16 + lr;        // j in [0,384)

  // weights -> MFMA B-fragments (192 VGPR/thread), shared across the 4 chunks
  S8 wf[4][12];
  #pragma unroll
  for (int q = 0; q < 4; q++){
    #pragma unroll
    for (int kc = 0; kc < 12; kc++){
      const float* p = wh + (size_t)(q * HH + jloc) * HH + kc * 32 + lq * 8;
      float4 v0 = *(const float4*)p;
      float4 v1 = *(const float4*)(p + 4);
      S8 t;
      t[0] = (short)f2bf(v0.x); t[1] = (short)f2bf(v0.y); t[2] = (short)f2bf(v0.z); t[3] = (short)f2bf(v0.w);
      t[4] = (short)f2bf(v1.x); t[5] = (short)f2bf(v1.y); t[6] = (short)f2bf(v1.z); t[7] = (short)f2bf(v1.w);
      wf[q][kc] = t;
    }
  }

  __shared__ __align__(16) U16 hl[4][16][408];   // per-chunk h tile, padded stride
  for (int i = tid; i < 4 * 16 * 408; i += 256) ((U16*)hl)[i] = 0;

  int lcs[16]; U32 oxp[16], oh[16];
  #pragma unroll
  for (int c = 0; c < 4; c++){
    #pragma unroll
    for (int rr = 0; rr < 4; rr++){
      int seq = c * 16 + lq * 4 + rr;
      int L = len_[seq];
      lcs[c * 4 + rr] = L;
      int t0 = dir ? (L - 1) : 0;
      oxp[c * 4 + rr] = (U32)(((seq * T_ + t0) * 3072 + dir * G4 + jloc) * 2);
      oh [c * 4 + rr] = (U32)(((seq * T_ + t0) * 768  + dir * HH + jloc) * 2);
    }
  }
  int clen0 = len_[0], clen1 = len_[16], clen2 = len_[32], clen3 = len_[48];
  int sxp = dir ? -6144 : 6144;   // byte strides per time step
  int sh  = dir ? -1536 : 1536;
  float cs[16], hs[16];
  #pragma unroll
  for (int i = 0; i < 16; i++){ cs[i] = 0.f; hs[i] = 0.f; }

  const char* xpB = (const char*)xp;
  char* hcB = (char*)hcat;
  U64 vp[12];
  U16 xv[16];

  #define IXV(C) { \
    _Pragma("unroll") \
    for (int rr = 0; rr < 4; rr++){ \
      const U16* p = (const U16*)(xpB + oxp[(C) * 4 + rr]); \
      xv[0 * 4 + rr] = p[0]; xv[1 * 4 + rr] = p[HH]; \
      xv[2 * 4 + rr] = p[2 * HH]; xv[3 * 4 + rr] = p[3 * HH]; \
    } }

  #define IPOLL(G, PAR) { \
    U64* src_ = hx + (size_t)(PAR) * 24576 + (size_t)(G) * 3072 + tid; \
    _Pragma("unroll") \
    for (int k = 0; k < 12; k++) \
      vp[k] = __hip_atomic_load(src_ + k * 256, __ATOMIC_RELAXED, __HIP_MEMORY_SCOPE_AGENT); \
  }

  #define CHECK_HL(C, R) { \
    U32 e_ = (U32)(R); \
    U64* src_ = hx + (size_t)((R) & 1) * 24576 + (size_t)(dir * 4 + (C)) * 3072 + tid; \
    for (;;){ \
      U32 bad = 0; \
      _Pragma("unroll") \
      for (int k = 0; k < 12; k++) bad |= (((U32)(vp[k] >> 32)) != e_) ? (1u << k) : 0u; \
      if (!bad) break; \
      _Pragma("unroll") \
      for (int k = 0; k < 12; k++) \
        if (bad & (1u << k)) \
          vp[k] = __hip_atomic_load(src_ + k * 256, __ATOMIC_RELAXED, __HIP_MEMORY_SCOPE_AGENT); \
    } \
    _Pragma("unroll") \
    for (int k = 0; k < 12; k++){ \
      int wi = tid + k * 256; int col = wi >> 3, p2 = wi & 7; \
      U32 lo = (U32)vp[k]; \
      hl[C][2 * p2 + 0][col] = (U16)lo; \
      hl[C][2 * p2 + 1][col] = (U16)(lo >> 16); \
    } }

  #define PHASE(C, CN, NCLEN) { \
    if (r){ CHECK_HL(C, r) __syncthreads(); } \
    bool nxt_same = (r < (NCLEN)); \
    { int nr_ = nxt_same ? r : (r + 1); \
      int ng_ = dir * 4 + (nxt_same ? (CN) : 0); \
      IPOLL(ng_, nr_ & 1) } \
    F4 acc0 = {0,0,0,0}, acc1 = {0,0,0,0}, acc2 = {0,0,0,0}, acc3 = {0,0,0,0}; \
    _Pragma("unroll") \
    for (int kc = 0; kc < 12; kc++){ \
      S8 a = *(const S8*)&hl[C][lr][kc * 32 + lq * 8]; \
      acc0 = __builtin_amdgcn_mfma_f32_16x16x32_bf16(a, wf[0][kc], acc0, 0, 0, 0); \
      acc1 = __builtin_amdgcn_mfma_f32_16x16x32_bf16(a, wf[1][kc], acc1, 0, 0, 0); \
      acc2 = __builtin_amdgcn_mfma_f32_16x16x32_bf16(a, wf[2][kc], acc2, 0, 0, 0); \
      acc3 = __builtin_amdgcn_mfma_f32_16x16x32_bf16(a, wf[3][kc], acc3, 0, 0, 0); \
    } \
    _Pragma("unroll") \
    for (int rr = 0; rr < 4; rr++){ \
      float ip = acc0[rr] + bf2f(xv[0 * 4 + rr]); \
      float fp = acc1[rr] + bf2f(xv[1 * 4 + rr]); \
      float gp = acc2[rr] + bf2f(xv[2 * 4 + rr]); \
      float op = acc3[rr] + bf2f(xv[3 * 4 + rr]); \
      float cn = sigm(fp) * cs[(C) * 4 + rr] + sigm(ip) * tanh_(gp); \
      float hn = sigm(op) * tanh_(cn); \
      if (r < lcs[(C) * 4 + rr]){ cs[(C) * 4 + rr] = cn; hs[(C) * 4 + rr] = hn; } \
    } \
    { U64 tg = ((U64)(U32)(r + 1)) << 32; \
      U64 w0 = ((U64)((U32)f2bf(hs[(C) * 4 + 0]) | ((U32)f2bf(hs[(C) * 4 + 1]) << 16))) | tg; \
      U64 w1 = ((U64)((U32)f2bf(hs[(C) * 4 + 2]) | ((U32)f2bf(hs[(C) * 4 + 3]) << 16))) | tg; \
      U64* dst_ = hx + (size_t)((r + 1) & 1) * 24576 + (size_t)(dir * 4 + (C)) * 3072 + jloc * 8 + lq * 2; \
      __hip_atomic_store(dst_ + 0, w0, __ATOMIC_RELAXED, __HIP_MEMORY_SCOPE_AGENT); \
      __hip_atomic_store(dst_ + 1, w1, __ATOMIC_RELAXED, __HIP_MEMORY_SCOPE_AGENT); } \
    _Pragma("unroll") \
    for (int rr = 0; rr < 4; rr++){ \
      if (r < lcs[(C) * 4 + rr]) *(U16*)(hcB + oh[(C) * 4 + rr]) = f2bf(hs[(C) * 4 + rr]); \
      bool adv = (r + 1) < lcs[(C) * 4 + rr]; \
      oxp[(C) * 4 + rr] += adv ? sxp : 0; \
      oh [(C) * 4 + rr] += adv ? sh  : 0; \
    } \
    if (nxt_same){ IXV(CN) } else { IXV(0) } \
  }

  __syncthreads();          // hl zero-init visible to all waves
  IXV(0)                    // prefetch xv for (r=0, chunk 0)
  int rounds = clen0;       // lengths sorted desc -> len_[0] is global max (=T)
  for (int r = 0; r < rounds; ++r){
    PHASE(0, 1, clen1)
    if (r < clen1) PHASE(1, 2, clen2)
    if (r < clen2) PHASE(2, 3, clen3)
    if (r < clen3) PHASE(3, 0, -1)
  }
  #undef PHASE
  #undef CHECK_HL
  #undef IPOLL
  #undef IXV
}

// ---------------- emissions: em = h @ lin_w^T + lin_b ----------------
__global__ __launch_bounds__(256) void k_em(const U16* hcat, const U16* lwb, const float* lin_b, float* em){
  __shared__ U16 lw[NL * DD];
  __shared__ U16 hs[8 * DD];
  int tid = threadIdx.x;
  for (int i = tid; i < NL * DD / 2; i += 256) ((U32*)lw)[i] = ((const U32*)lwb)[i];
  size_t r0 = (size_t)blockIdx.x * 8;
  const U32* hsrc = (const U32*)(hcat + r0 * DD);
  for (int i = tid; i < 8 * DD / 2; i += 256) ((U32*)hs)[i] = hsrc[i];
  __syncthreads();
  for (int e = tid; e < 8 * NL; e += 256){
    int rr = e / NL, ll = e % NL;
    const U16* hp = &hs[rr * DD];
    const U16* wp = &lw[ll * DD];
    float s = 0.f;
    #pragma unroll 8
    for (int k = 0; k < DD; k += 2){
      U32 hv = *(const U32*)&hp[k];
      U32 wv = *(const U32*)&wp[k];
      s = fmaf(__uint_as_float(hv << 16), __uint_as_float(wv << 16), s);
      s = fmaf(__uint_as_float(hv & 0xffff0000u), __uint_as_float(wv & 0xffff0000u), s);
    }
    em[(r0 + rr) * NL + ll] = s + lin_b[ll];
  }
}

// ---------------- CRF: single-wave, shuffle-broadcast alpha recursion ----------------
__global__ void k_crf(const float* em, const int* labels, const int* len_, const float* trans,
                      const float* startt, const float* endt, float* score){
  int b = blockIdx.x, l = threadIdx.x;
  int L = len_[b];
  const int* lab = labels + b * T_;
  const float* emb = em + (size_t)b * T_ * NL;
  float part = 0.f;
  for (int t = 1 + l; t < L; t += 64){
    int lp = lab[t - 1], lc = lab[t];
    part += trans[lp * NL + lc] + emb[(size_t)t * NL + lc];
  }
  #pragma unroll
  for (int o = 32; o >= 1; o >>= 1) part += __shfl_xor(part, o);
  float num = part + startt[lab[0]] + emb[lab[0]] + endt[lab[L - 1]];
  bool act = l < NL;
  int jj = act ? l : (NL - 1);
  float tc[NL];
  #pragma unroll
  for (int i = 0; i < NL; i++) tc[i] = trans[i * NL + jj];
  float a = startt[jj] + emb[jj];
  for (int t = 1; t < L; ++t){
    float vv[NL];
    float mx = -3.0e38f;
    #pragma unroll
    for (int i = 0; i < NL; i++){ vv[i] = __shfl(a, i) + tc[i]; mx = fmaxf(mx, vv[i]); }
    float s = 0.f;
    #pragma unroll
    for (int i = 0; i < NL; i++) s += __expf(vv[i] - mx);
    a = mx + __logf(s) + emb[(size_t)t * NL + jj];
  }
  float val = act ? (a + endt[jj]) : -3.0e38f;
  float mx = val;
  #pragma unroll
  for (int o = 32; o >= 1; o >>= 1) mx = fmaxf(mx, __shfl_xor(mx, o));
  float se = __expf(val - mx);
  #pragma unroll
  for (int o = 32; o >= 1; o >>= 1) se += __shfl_xor(se, o);
  float logZ = mx + __logf(se);
  if (l == 0) score[b] = num - logZ;
}

__global__ void k_final(const float* score, float* out){
  int l = threadIdx.x;
  float v = score[l];
  #pragma unroll
  for (int o = 32; o >= 1; o >>= 1) v += __shfl_xor(v, o);
  if (l == 0) out[0] = -v / 64.f;
}

__global__ void k_sentinel(float* out){ out[0] = -12345.f; }

extern "C" void kernel_launch(void* const* d_in, const int* in_sizes, int n_in,
                              void* d_out, int out_size, void* d_ws, size_t ws_size,
                              hipStream_t stream){
  const float* x      = (const float*)d_in[0];
  const void*  mask   = d_in[1];
  const int*   labels = (const int*)d_in[2];
  const float* w_ih_f = (const float*)d_in[4];
  const float* w_hh_f = (const float*)d_in[5];
  const float* b_f    = (const float*)d_in[6];
  const float* w_ih_b = (const float*)d_in[7];
  const float* w_hh_b = (const float*)d_in[8];
  const float* b_b    = (const float*)d_in[9];
  const float* lin_w  = (const float*)d_in[10];
  const float* lin_b  = (const float*)d_in[11];
  const float* trans  = (const float*)d_in[12];
  const float* startt = (const float*)d_in[13];
  const float* endt   = (const float*)d_in[14];
  float* out = (float*)d_out;

  const size_t WS_NEEDED = 261158912;
  if (ws_size < WS_NEEDED){
    k_sentinel<<<1, 1, 0, stream>>>(out);
    return;
  }

  char* ws = (char*)d_ws;
  size_t off = 0;
  auto take = [&](size_t bytes) -> char* {
    char* p = ws + off;
    off += (bytes + 255) & ~(size_t)255;
    return p;
  };
  U16*  xp    = (U16*)take((size_t)32768 * 3072 * 2);   // 201.3 MB
  U16*  hcat  = (U16*)take((size_t)32768 * 768 * 2);    // 50.3 MB (doubles as x_bf16)
  U16*  wcat  = (U16*)take((size_t)3072 * 768 * 2);
  U16*  lwb   = (U16*)take((size_t)NL * 768 * 2);
  float* bcat = (float*)take(3072 * 4);
  int*  lens  = (int*)take(256);
  U64*  hx    = (U64*)take((size_t)2 * 8 * 3072 * 8);   // 384 KB tagged exchange
  float* em   = (float*)take((size_t)32768 * NL * 4);
  float* score= (float*)take(256);
  U16*  xbf   = hcat;   // alias: x_bf16 lives here until GEMM done, then region becomes h_cat

  hipMemsetAsync(hx, 0, (size_t)2 * 8 * 3072 * 8, stream);  // clear tags (replay safety)
  k_pre<<<3136, 256, 0, stream>>>(x, (U64*)xbf, (const U32*)mask, lens,
                                  w_ih_f, w_ih_b, lin_w, b_f, b_b, wcat, lwb, bcat);
  k_gemm<<<6144, 256, 0, stream>>>(xbf, wcat, bcat, xp);
  k_rec<<<12, 256, 0, stream>>>(xp, w_hh_f, w_hh_b, lens, hcat, hx);
  k_em<<<4096, 256, 0, stream>>>(hcat, lwb, lin_b, em);
  k_crf<<<64, 64, 0, stream>>>(em, labels, lens, trans, startt, endt, score);
  k_final<<<1, 64, 0, stream>>>(score, out);
}